// Round 5
// baseline (405.118 us; speedup 1.0000x reference)
//
#include <hip/hip_runtime.h>
#include <stdint.h>

#define T_SEQ   2048
#define DMODEL  1024
#define NHEADS  16
#define HDIM    64
#define BATCH   4
#define MROWS   (BATCH * T_SEQ)   // 8192
// Q pre-scale: 1/sqrt(64) * log2(e)  (softmax runs in exp2 domain)
#define QSCALE  0.18033688011112042f
// defer-max threshold (log2 units): skip O/l rescale unless max grew by >6
#define DEFER_THR 6.0f

typedef __attribute__((ext_vector_type(4))) short bf16x4;
typedef __attribute__((ext_vector_type(8))) short bf16x8;
typedef __attribute__((ext_vector_type(4))) float f32x4;

__device__ __forceinline__ float b2f(unsigned short u) {
    union { unsigned int i; float f; } x;
    x.i = ((unsigned int)u) << 16;
    return x.f;
}

__device__ __forceinline__ unsigned short f2b(float f) {
    union { float f; unsigned int i; } x;
    x.f = f;
    unsigned int r = x.i + 0x7FFFu + ((x.i >> 16) & 1u);  // RNE
    return (unsigned short)(r >> 16);
}

// raw v_exp_f32 (input in log2 domain)
__device__ __forceinline__ float fexp2(float x) {
#if __has_builtin(__builtin_amdgcn_exp2f)
    return __builtin_amdgcn_exp2f(x);
#else
    return __expf(x * 0.6931471805599453f);
#endif
}

// pack two fp32 -> packed bf16 pair (low = a, high = b)
__device__ __forceinline__ unsigned int pack2(float a, float b) {
#if __has_builtin(__builtin_amdgcn_cvt_pk_bf16_f32)
    auto r = __builtin_amdgcn_cvt_pk_bf16_f32(a, b);
    unsigned int u;
    __builtin_memcpy(&u, &r, 4);
    return u;
#else
    return ((unsigned int)f2b(a)) | (((unsigned int)f2b(b)) << 16);
#endif
}

// tree max of a 4x f32x4 tile (depth 4; clang fuses pairs to v_max3 where it can)
__device__ __forceinline__ float max16(const f32x4 s[4]) {
    const float a = fmaxf(fmaxf(s[0][0], s[0][1]), fmaxf(s[0][2], s[0][3]));
    const float b = fmaxf(fmaxf(s[1][0], s[1][1]), fmaxf(s[1][2], s[1][3]));
    const float c = fmaxf(fmaxf(s[2][0], s[2][1]), fmaxf(s[2][2], s[2][3]));
    const float d = fmaxf(fmaxf(s[3][0], s[3][1]), fmaxf(s[3][2], s[3][3]));
    return fmaxf(fmaxf(a, b), fmaxf(c, d));
}

// online softmax (exp2 domain) for one 16x(4x16) score tile
__device__ __forceinline__ void online_softmax(
    const f32x4 sg[4], float& m_, float& l_, f32x4 o_[4], bf16x4 pf_[4])
{
    float mc = max16(sg);
    mc = fmaxf(mc, __shfl_xor(mc, 16));
    mc = fmaxf(mc, __shfl_xor(mc, 32));
    if (__any(mc > m_ + DEFER_THR)) {          // defer-max: rescale rarely
        const float mn    = fmaxf(m_, mc);
        const float alpha = fexp2(m_ - mn);
        l_ *= alpha;
        #pragma unroll
        for (int dt = 0; dt < 4; dt++)
            #pragma unroll
            for (int r = 0; r < 4; r++) o_[dt][r] *= alpha;
        m_ = mn;
    }
    float ps = 0.f;
    #pragma unroll
    for (int s = 0; s < 4; s++) {
        const float p0 = fexp2(sg[s][0] - m_);
        const float p1 = fexp2(sg[s][1] - m_);
        const float p2 = fexp2(sg[s][2] - m_);
        const float p3 = fexp2(sg[s][3] - m_);
        ps += (p0 + p1) + (p2 + p3);
        uint2 u;
        u.x = pack2(p0, p1);
        u.y = pack2(p2, p3);
        pf_[s] = *(bf16x4*)&u;
    }
    ps += __shfl_xor(ps, 16);
    ps += __shfl_xor(ps, 32);
    l_ += ps;
}

// async global->LDS, 16 B per lane; dest = lds base (wave-uniform) + lane*16
__device__ __forceinline__ void gl_lds16(const unsigned short* g, unsigned short* l) {
    __builtin_amdgcn_global_load_lds(
        (const __attribute__((address_space(1))) void*)g,
        (__attribute__((address_space(3))) void*)l,
        16, 0, 0);
}

// ---------------------------------------------------------------------------
// fp32 -> bf16 elementwise convert
// ---------------------------------------------------------------------------
__global__ __launch_bounds__(256) void cvt_bf16(
    const float* __restrict__ in, unsigned short* __restrict__ out, int n)
{
    const int i = (blockIdx.x * 256 + threadIdx.x) * 4;
    if (i + 3 < n) {
        const float4 v = *(const float4*)(in + i);
        ushort4 o;
        o.x = f2b(v.x); o.y = f2b(v.y); o.z = f2b(v.z); o.w = f2b(v.w);
        *(ushort4*)(out + i) = o;
    }
}

// ---------------------------------------------------------------------------
// fp32 [K][N] -> bf16 [N][K] transpose+convert, 32x32 LDS tile
// ---------------------------------------------------------------------------
__global__ __launch_bounds__(256) void cvt_tr(
    const float* __restrict__ W, unsigned short* __restrict__ WT, int K, int N)
{
    __shared__ unsigned short s[32][33];
    const int n0 = blockIdx.x * 32, k0 = blockIdx.y * 32;
    const int tx = threadIdx.x & 31, ty = threadIdx.x >> 5;   // ty 0..7
    #pragma unroll
    for (int i = 0; i < 4; i++)
        s[ty + 8 * i][tx] = f2b(W[(size_t)(k0 + ty + 8 * i) * N + n0 + tx]);
    __syncthreads();
    #pragma unroll
    for (int i = 0; i < 4; i++)
        WT[(size_t)(n0 + ty + 8 * i) * K + k0 + tx] = s[tx][ty + 8 * i];
}

// ---------------------------------------------------------------------------
// bf16 MFMA GEMM: C[M][N] = A[M][Kd] * BT[N][Kd]^T + bias[N]
// 128x128 tile, BK=64 (verified R14: -15% vs BK=32). 256 thr = 4 waves (2x2).
// 16 gl_lds16 calls per buffer; XOR swizzle c^(row&7) on source + read side.
// ---------------------------------------------------------------------------
__global__ __launch_bounds__(256) void gemm_mfma(
    const unsigned short* __restrict__ A,
    const unsigned short* __restrict__ BT,
    const float* __restrict__ bias,
    int N, int Kd, int mode,
    unsigned short* __restrict__ Oq,
    unsigned short* __restrict__ Ok,
    unsigned short* __restrict__ Ov,
    float* __restrict__ Of)
{
    __shared__ __align__(16) unsigned short aS[128 * 64];
    __shared__ __align__(16) unsigned short bS[128 * 64];

    const int tid  = threadIdx.x;
    const int lane = tid & 63;
    const int wave = tid >> 6;
    const int row  = lane & 15;
    const int quad = lane >> 4;
    const int wm   = wave >> 1;
    const int wn   = wave & 1;
    const int m0   = blockIdx.y * 128;
    const int n0   = blockIdx.x * 128;

    // staging geometry: one gload = 64 lanes x 16B = 8 rows x 64 k (128B/row)
    const int srow = lane >> 3;            // 0..7  local row
    const int c8   = lane & 7;             // 0..7  dest chunk (16B units)
    const int csw  = c8 ^ srow;            // pre-swizzled SOURCE chunk

    f32x4 acc[4][4];
    const f32x4 z = {0.f, 0.f, 0.f, 0.f};
    #pragma unroll
    for (int i = 0; i < 4; i++)
        #pragma unroll
        for (int j = 0; j < 4; j++) acc[i][j] = z;

    for (int k0 = 0; k0 < Kd; k0 += 64) {
        __syncthreads();   // all waves done reading previous tile
        #pragma unroll
        for (int c = 0; c < 4; c++) {
            gl_lds16(A  + (size_t)(m0 + c * 32 + wave * 8 + srow) * Kd + k0 + csw * 8,
                     &aS[c * 2048 + wave * 512]);
            gl_lds16(BT + (size_t)(n0 + c * 32 + wave * 8 + srow) * Kd + k0 + csw * 8,
                     &bS[c * 2048 + wave * 512]);
        }
        __syncthreads();   // drains vmcnt -> LDS valid

        #pragma unroll
        for (int ks = 0; ks < 2; ks++) {
            bf16x8 af[4], bf[4];
            const int cp = ((ks * 4 + quad) ^ (row & 7)) * 8;   // swizzled read chunk
            #pragma unroll
            for (int t = 0; t < 4; t++) {
                af[t] = *(const bf16x8*)(aS + (wm * 64 + t * 16 + row) * 64 + cp);
                bf[t] = *(const bf16x8*)(bS + (wn * 64 + t * 16 + row) * 64 + cp);
            }
            #pragma unroll
            for (int i = 0; i < 4; i++)
                #pragma unroll
                for (int j = 0; j < 4; j++)
                    acc[i][j] = __builtin_amdgcn_mfma_f32_16x16x32_bf16(af[i], bf[j], acc[i][j], 0, 0, 0);
        }
    }

    if (mode == 0) {
        #pragma unroll
        for (int j = 0; j < 4; j++) {
            const int n  = n0 + wn * 64 + j * 16 + row;
            const float bi = bias[n];
            const int which = n >> 10;
            const int rem   = n & 1023;
            const int h     = rem >> 6;
            const int d     = rem & 63;
            #pragma unroll
            for (int i = 0; i < 4; i++) {
                const int mbase = m0 + wm * 64 + i * 16 + quad * 4;
                #pragma unroll
                for (int r = 0; r < 4; r++) {
                    const int m = mbase + r;
                    const int b = m >> 11;
                    const int t = m & 2047;
                    const int bh = b * NHEADS + h;
                    const float v = acc[i][j][r] + bi;
                    if (which == 0) {
                        Oq[((size_t)bh * T_SEQ + t) * HDIM + d] = f2b(v * QSCALE);
                    } else if (which == 1) {
                        Ok[((size_t)bh * T_SEQ + t) * HDIM + d] = f2b(v);
                    } else {
                        Ov[((size_t)bh * HDIM + d) * T_SEQ + t] = f2b(v);
                    }
                }
            }
        }
    } else {
        #pragma unroll
        for (int j = 0; j < 4; j++) {
            const int n  = n0 + wn * 64 + j * 16 + row;
            const float bi = bias[n];
            #pragma unroll
            for (int i = 0; i < 4; i++) {
                const int mbase = m0 + wm * 64 + i * 16 + quad * 4;
                #pragma unroll
                for (int r = 0; r < 4; r++)
                    Of[(size_t)(mbase + r) * N + n] = acc[i][j][r] + bi;
            }
        }
    }
}

// ---------------------------------------------------------------------------
// MFMA flash attention — R15: FOUR q-tiles per block ("double-q").
// Block P in 0..7 owns L-super [128P,128P+128) and H-super [128(15-P),+128),
// split into 4 per-wave 16-row tiles: t0=H1 (widest), t1=H0, t2=L1, t3=L0.
// Active tile-slots per block = 66 for every P (balanced); iterations per
// head drop 392 -> 200; K-frag ds_reads serve 2 tiles/group, V-frag ds_reads
// serve up to 4 tiles. Staging redundancy halves (8 blocks/head vs 16).
// Setprio REMOVED (R3 post-mortem: lockstep 4-wave block = m190 null case,
// cost ~7 us). Defer-max + tree-max kept.
// ---------------------------------------------------------------------------
__global__ __launch_bounds__(256) void attn_mfma(
    const unsigned short* __restrict__ Q,   // [bh][t][64] bf16 (scaled, log2e)
    const unsigned short* __restrict__ K,   // [bh][t][64] bf16
    const unsigned short* __restrict__ VT,  // [bh][64][T] bf16
    unsigned short* __restrict__ Out)       // [B*T][DMODEL] bf16
{
    __shared__ __align__(16) unsigned short kS[2][64 * 72];
    __shared__ __align__(16) unsigned short vS[2][64 * 72];

    const int tid  = threadIdx.x;
    const int lane = tid & 63;
    const int wave = tid >> 6;
    const int row  = lane & 15;
    const int quad = lane >> 4;

    const int bh = blockIdx.x;
    const int b  = bh >> 4;
    const int h  = bh & 15;
    const int P  = blockIdx.y;                 // 0..7
    const int qa = 128 * P;                    // L-supertile base
    const int qh = 128 * (15 - P);             // H-supertile base
    int q0[4];
    q0[0] = qh + 64 + 16 * wave;               // H1 (widest causal extent)
    q0[1] = qh      + 16 * wave;               // H0
    q0[2] = qa + 64 + 16 * wave;               // L1
    q0[3] = qa      + 16 * wave;               // L0
    const int kend = qh + 128;                 // WG-uniform loop bound

    const size_t qkbase = (size_t)bh * T_SEQ * HDIM;
    const size_t vtbase = (size_t)bh * HDIM * T_SEQ;

    // staging geometry: pass covers 2048 elems; thread -> (krow, chunk)
    const int krow0 = tid >> 3;          // 0..31
    const int c0    = tid & 7;           // 0..7
    const int lds0  = krow0 * 72 + c0 * 8;
    const int lds1  = (krow0 + 32) * 72 + c0 * 8;
    const int flat0 = tid * 8;           // = krow0*64 + c0*8

    // Q fragments (4 tiles x 2 halves)
    bf16x8 qf0[4], qf1[4];
    #pragma unroll
    for (int t = 0; t < 4; t++) {
        const unsigned short* qp = Q + qkbase + (size_t)(q0[t] + row) * HDIM + quad * 8;
        qf0[t] = *(const bf16x8*)qp;
        qf1[t] = *(const bf16x8*)(qp + 32);
    }

    const f32x4 z = {0.f, 0.f, 0.f, 0.f};
    f32x4 o[4][4];
    float m[4], l[4];
    #pragma unroll
    for (int t = 0; t < 4; t++) {
        #pragma unroll
        for (int dt = 0; dt < 4; dt++) o[t][dt] = z;
        m[t] = -1e30f;
        l[t] = 0.f;
    }

    // prefetch tile 0
    uint4 pk0 = *(const uint4*)(K  + qkbase + flat0);
    uint4 pk1 = *(const uint4*)(K  + qkbase + flat0 + 2048);
    uint4 pv0 = *(const uint4*)(VT + vtbase + (size_t)krow0        * T_SEQ + c0 * 8);
    uint4 pv1 = *(const uint4*)(VT + vtbase + (size_t)(krow0 + 32) * T_SEQ + c0 * 8);

    int buf = 0;
    for (int kb = 0; kb < kend; kb += 64) {
        // write staged tile to LDS[buf]
        *(uint4*)&kS[buf][lds0] = pk0;
        *(uint4*)&kS[buf][lds1] = pk1;
        *(uint4*)&vS[buf][lds0] = pv0;
        *(uint4*)&vS[buf][lds1] = pv1;
        __syncthreads();

        // prefetch next tile (overlaps with compute below)
        if (kb + 64 < kend) {
            const int kn = kb + 64;
            pk0 = *(const uint4*)(K  + qkbase + (size_t)kn * HDIM + flat0);
            pk1 = *(const uint4*)(K  + qkbase + (size_t)kn * HDIM + flat0 + 2048);
            pv0 = *(const uint4*)(VT + vtbase + (size_t)krow0        * T_SEQ + kn + c0 * 8);
            pv1 = *(const uint4*)(VT + vtbase + (size_t)(krow0 + 32) * T_SEQ + kn + c0 * 8);
        }

        bf16x4 pf[4][4];    // P fragments per tile per s-step (guarded use)

        // ---- QK^T + softmax, two groups of two tiles sharing K fragments ----
        #pragma unroll
        for (int g = 0; g < 2; g++) {
            const int t0 = 2 * g;       // wider tile of the group
            const int t1 = 2 * g + 1;
            if (kb <= q0[t0]) {         // group active (wave-uniform)
                f32x4 sg0[4], sg1[4];
                #pragma unroll
                for (int s = 0; s < 4; s++) {
                    const int kbs = kb + s * 16;
                    if (kbs <= q0[t0]) {
                        const unsigned short* kp = &kS[buf][(s * 16 + row) * 72 + quad * 8];
                        const bf16x8 kf0 = *(const bf16x8*)kp;
                        const bf16x8 kf1 = *(const bf16x8*)(kp + 32);
                        f32x4 a = z;
                        a = __builtin_amdgcn_mfma_f32_16x16x32_bf16(kf0, qf0[t0], a, 0, 0, 0);
                        a = __builtin_amdgcn_mfma_f32_16x16x32_bf16(kf1, qf1[t0], a, 0, 0, 0);
                        if (kbs == q0[t0]) {
                            #pragma unroll
                            for (int r = 0; r < 4; r++)
                                if (quad * 4 + r > row) a[r] = -1e30f;
                        }
                        sg0[s] = a;
                        if (kbs <= q0[t1]) {
                            f32x4 c = z;
                            c = __builtin_amdgcn_mfma_f32_16x16x32_bf16(kf0, qf0[t1], c, 0, 0, 0);
                            c = __builtin_amdgcn_mfma_f32_16x16x32_bf16(kf1, qf1[t1], c, 0, 0, 0);
                            if (kbs == q0[t1]) {
                                #pragma unroll
                                for (int r = 0; r < 4; r++)
                                    if (quad * 4 + r > row) c[r] = -1e30f;
                            }
                            sg1[s] = c;
                        } else {
                            #pragma unroll
                            for (int r = 0; r < 4; r++) sg1[s][r] = -1e30f;
                        }
                    } else {
                        #pragma unroll
                        for (int r = 0; r < 4; r++) { sg0[s][r] = -1e30f; sg1[s][r] = -1e30f; }
                    }
                }
                online_softmax(sg0, m[t0], l[t0], o[t0], pf[t0]);
                if (kb <= q0[t1])
                    online_softmax(sg1, m[t1], l[t1], o[t1], pf[t1]);
            }
        }

        // ---- PV from LDS V^T tile: one vf read feeds up to 4 tiles ----
        #pragma unroll
        for (int s = 0; s < 4; s++) {
            const int kbs = kb + s * 16;
            if (kbs <= q0[0]) {
                #pragma unroll
                for (int dt = 0; dt < 4; dt++) {
                    const bf16x4 vf = *(const bf16x4*)&vS[buf][
                        (dt * 16 + row) * 72 + (s * 2 + (quad >> 1)) * 8 + (quad & 1) * 4];
                    o[0][dt] = __builtin_amdgcn_mfma_f32_16x16x16bf16_1k(vf, pf[0][s], o[0][dt], 0, 0, 0);
                    if (kbs <= q0[1])
                        o[1][dt] = __builtin_amdgcn_mfma_f32_16x16x16bf16_1k(vf, pf[1][s], o[1][dt], 0, 0, 0);
                    if (kbs <= q0[2])
                        o[2][dt] = __builtin_amdgcn_mfma_f32_16x16x16bf16_1k(vf, pf[2][s], o[2][dt], 0, 0, 0);
                    if (kbs <= q0[3])
                        o[3][dt] = __builtin_amdgcn_mfma_f32_16x16x16bf16_1k(vf, pf[3][s], o[3][dt], 0, 0, 0);
                }
            }
        }

        buf ^= 1;
    }

    // ---- epilogue: all four tiles ----
    #pragma unroll
    for (int t = 0; t < 4; t++) {
        const float rl = 1.f / l[t];
        unsigned short* op = Out + ((size_t)(b * T_SEQ + q0[t] + row)) * DMODEL + h * HDIM + quad * 4;
        #pragma unroll
        for (int dt = 0; dt < 4; dt++) {
            uint2 u;
            u.x = pack2(o[t][dt][0] * rl, o[t][dt][1] * rl);
            u.y = pack2(o[t][dt][2] * rl, o[t][dt][3] * rl);
            *(uint2*)(op + dt * 16) = u;
        }
    }
}

extern "C" void kernel_launch(void* const* d_in, const int* in_sizes, int n_in,
                              void* d_out, int out_size, void* d_ws, size_t ws_size,
                              hipStream_t stream)
{
    const float* x    = (const float*)d_in[0];
    const float* Wqkv = (const float*)d_in[1];
    const float* bqkv = (const float*)d_in[2];
    const float* Wout = (const float*)d_in[3];
    const float* bout = (const float*)d_in[4];
    float* out = (float*)d_out;

    // workspace (MiB offsets): xb 0..16 | WqkvT 16..22 | WoutT 22..24 |
    // Qb 24..40 | Kb 40..56 | Vt 56..72 | Ab 72..88
    char* ws = (char*)d_ws;
    unsigned short* xb    = (unsigned short*)(ws + (size_t)0  * 1024 * 1024);
    unsigned short* WqkvT = (unsigned short*)(ws + (size_t)16 * 1024 * 1024);
    unsigned short* WoutT = (unsigned short*)(ws + (size_t)22 * 1024 * 1024);
    unsigned short* Qb    = (unsigned short*)(ws + (size_t)24 * 1024 * 1024);
    unsigned short* Kb    = (unsigned short*)(ws + (size_t)40 * 1024 * 1024);
    unsigned short* Vt    = (unsigned short*)(ws + (size_t)56 * 1024 * 1024);
    unsigned short* Ab    = (unsigned short*)(ws + (size_t)72 * 1024 * 1024);

    // 0) converts / transposes
    cvt_bf16<<<dim3(MROWS * DMODEL / 1024), 256, 0, stream>>>(x, xb, MROWS * DMODEL);
    cvt_tr<<<dim3(3 * DMODEL / 32, DMODEL / 32), 256, 0, stream>>>(Wqkv, WqkvT, DMODEL, 3 * DMODEL);
    cvt_tr<<<dim3(DMODEL / 32, DMODEL / 32), 256, 0, stream>>>(Wout, WoutT, DMODEL, DMODEL);

    // 1) qkv = x @ W_qkv + b_qkv -> Qb (scaled, log2e folded), Kb, Vt
    gemm_mfma<<<dim3(3 * DMODEL / 128, MROWS / 128), 256, 0, stream>>>(
        xb, WqkvT, bqkv, 3 * DMODEL, DMODEL, 0, Qb, Kb, Vt, nullptr);

    // 2) causal MFMA flash attention -> Ab bf16 (8 blocks/head, 4 tiles each)
    attn_mfma<<<dim3(BATCH * NHEADS, 8), 256, 0, stream>>>(Qb, Kb, Vt, Ab);

    // 3) out = Ab @ W_out + b_out (fp32 out)
    gemm_mfma<<<dim3(DMODEL / 128, MROWS / 128), 256, 0, stream>>>(
        Ab, WoutT, bout, DMODEL, DMODEL, 1, nullptr, nullptr, nullptr, out);
}

// Round 6
// 298.791 us; speedup vs baseline: 1.3559x; 1.3559x over previous
//
#include <hip/hip_runtime.h>
#include <stdint.h>

#define T_SEQ   2048
#define DMODEL  1024
#define NHEADS  16
#define HDIM    64
#define BATCH   4
#define MROWS   (BATCH * T_SEQ)   // 8192
// Q pre-scale: 1/sqrt(64) * log2(e)  (softmax runs in exp2 domain)
#define QSCALE  0.18033688011112042f
// defer-max threshold (log2 units): skip O/l rescale unless max grew by >6
#define DEFER_THR 6.0f

typedef __attribute__((ext_vector_type(4))) short bf16x4;
typedef __attribute__((ext_vector_type(8))) short bf16x8;
typedef __attribute__((ext_vector_type(4))) float f32x4;

__device__ __forceinline__ float b2f(unsigned short u) {
    union { unsigned int i; float f; } x;
    x.i = ((unsigned int)u) << 16;
    return x.f;
}

__device__ __forceinline__ unsigned short f2b(float f) {
    union { float f; unsigned int i; } x;
    x.f = f;
    unsigned int r = x.i + 0x7FFFu + ((x.i >> 16) & 1u);  // RNE
    return (unsigned short)(r >> 16);
}

// raw v_exp_f32 (input in log2 domain)
__device__ __forceinline__ float fexp2(float x) {
#if __has_builtin(__builtin_amdgcn_exp2f)
    return __builtin_amdgcn_exp2f(x);
#else
    return __expf(x * 0.6931471805599453f);
#endif
}

// pack two fp32 -> packed bf16 pair (low = a, high = b)
__device__ __forceinline__ unsigned int pack2(float a, float b) {
#if __has_builtin(__builtin_amdgcn_cvt_pk_bf16_f32)
    auto r = __builtin_amdgcn_cvt_pk_bf16_f32(a, b);
    unsigned int u;
    __builtin_memcpy(&u, &r, 4);
    return u;
#else
    return ((unsigned int)f2b(a)) | (((unsigned int)f2b(b)) << 16);
#endif
}

// tree max of a 4x f32x4 tile (depth 4; clang fuses pairs to v_max3 where it can)
__device__ __forceinline__ float max16(const f32x4 s[4]) {
    const float a = fmaxf(fmaxf(s[0][0], s[0][1]), fmaxf(s[0][2], s[0][3]));
    const float b = fmaxf(fmaxf(s[1][0], s[1][1]), fmaxf(s[1][2], s[1][3]));
    const float c = fmaxf(fmaxf(s[2][0], s[2][1]), fmaxf(s[2][2], s[2][3]));
    const float d = fmaxf(fmaxf(s[3][0], s[3][1]), fmaxf(s[3][2], s[3][3]));
    return fmaxf(fmaxf(a, b), fmaxf(c, d));
}

// online softmax (exp2 domain) for one 16x(4x16) score tile
__device__ __forceinline__ void online_softmax(
    const f32x4 sg[4], float& m_, float& l_, f32x4 o_[4], bf16x4 pf_[4])
{
    float mc = max16(sg);
    mc = fmaxf(mc, __shfl_xor(mc, 16));
    mc = fmaxf(mc, __shfl_xor(mc, 32));
    if (__any(mc > m_ + DEFER_THR)) {          // defer-max: rescale rarely
        const float mn    = fmaxf(m_, mc);
        const float alpha = fexp2(m_ - mn);
        l_ *= alpha;
        #pragma unroll
        for (int dt = 0; dt < 4; dt++)
            #pragma unroll
            for (int r = 0; r < 4; r++) o_[dt][r] *= alpha;
        m_ = mn;
    }
    float ps = 0.f;
    #pragma unroll
    for (int s = 0; s < 4; s++) {
        const float p0 = fexp2(sg[s][0] - m_);
        const float p1 = fexp2(sg[s][1] - m_);
        const float p2 = fexp2(sg[s][2] - m_);
        const float p3 = fexp2(sg[s][3] - m_);
        ps += (p0 + p1) + (p2 + p3);
        uint2 u;
        u.x = pack2(p0, p1);
        u.y = pack2(p2, p3);
        pf_[s] = *(bf16x4*)&u;
    }
    ps += __shfl_xor(ps, 16);
    ps += __shfl_xor(ps, 32);
    l_ += ps;
}

// async global->LDS, 16 B per lane; dest = lds base (wave-uniform) + lane*16
__device__ __forceinline__ void gl_lds16(const unsigned short* g, unsigned short* l) {
    __builtin_amdgcn_global_load_lds(
        (const __attribute__((address_space(1))) void*)g,
        (__attribute__((address_space(3))) void*)l,
        16, 0, 0);
}

// ---------------------------------------------------------------------------
// fp32 -> bf16 elementwise convert
// ---------------------------------------------------------------------------
__global__ __launch_bounds__(256) void cvt_bf16(
    const float* __restrict__ in, unsigned short* __restrict__ out, int n)
{
    const int i = (blockIdx.x * 256 + threadIdx.x) * 4;
    if (i + 3 < n) {
        const float4 v = *(const float4*)(in + i);
        ushort4 o;
        o.x = f2b(v.x); o.y = f2b(v.y); o.z = f2b(v.z); o.w = f2b(v.w);
        *(ushort4*)(out + i) = o;
    }
}

// ---------------------------------------------------------------------------
// fp32 [K][N] -> bf16 [N][K] transpose+convert, 32x32 LDS tile
// ---------------------------------------------------------------------------
__global__ __launch_bounds__(256) void cvt_tr(
    const float* __restrict__ W, unsigned short* __restrict__ WT, int K, int N)
{
    __shared__ unsigned short s[32][33];
    const int n0 = blockIdx.x * 32, k0 = blockIdx.y * 32;
    const int tx = threadIdx.x & 31, ty = threadIdx.x >> 5;   // ty 0..7
    #pragma unroll
    for (int i = 0; i < 4; i++)
        s[ty + 8 * i][tx] = f2b(W[(size_t)(k0 + ty + 8 * i) * N + n0 + tx]);
    __syncthreads();
    #pragma unroll
    for (int i = 0; i < 4; i++)
        WT[(size_t)(n0 + ty + 8 * i) * K + k0 + tx] = s[tx][ty + 8 * i];
}

// ---------------------------------------------------------------------------
// bf16 MFMA GEMM: C[M][N] = A[M][Kd] * BT[N][Kd]^T + bias[N]
// 128x128 tile, BK=64 (verified R14: -15% vs BK=32). 256 thr = 4 waves (2x2).
// 16 gl_lds16 calls per buffer; XOR swizzle c^(row&7) on source + read side.
// ---------------------------------------------------------------------------
__global__ __launch_bounds__(256) void gemm_mfma(
    const unsigned short* __restrict__ A,
    const unsigned short* __restrict__ BT,
    const float* __restrict__ bias,
    int N, int Kd, int mode,
    unsigned short* __restrict__ Oq,
    unsigned short* __restrict__ Ok,
    unsigned short* __restrict__ Ov,
    float* __restrict__ Of)
{
    __shared__ __align__(16) unsigned short aS[128 * 64];
    __shared__ __align__(16) unsigned short bS[128 * 64];

    const int tid  = threadIdx.x;
    const int lane = tid & 63;
    const int wave = tid >> 6;
    const int row  = lane & 15;
    const int quad = lane >> 4;
    const int wm   = wave >> 1;
    const int wn   = wave & 1;
    const int m0   = blockIdx.y * 128;
    const int n0   = blockIdx.x * 128;

    // staging geometry: one gload = 64 lanes x 16B = 8 rows x 64 k (128B/row)
    const int srow = lane >> 3;            // 0..7  local row
    const int c8   = lane & 7;             // 0..7  dest chunk (16B units)
    const int csw  = c8 ^ srow;            // pre-swizzled SOURCE chunk

    f32x4 acc[4][4];
    const f32x4 z = {0.f, 0.f, 0.f, 0.f};
    #pragma unroll
    for (int i = 0; i < 4; i++)
        #pragma unroll
        for (int j = 0; j < 4; j++) acc[i][j] = z;

    for (int k0 = 0; k0 < Kd; k0 += 64) {
        __syncthreads();   // all waves done reading previous tile
        #pragma unroll
        for (int c = 0; c < 4; c++) {
            gl_lds16(A  + (size_t)(m0 + c * 32 + wave * 8 + srow) * Kd + k0 + csw * 8,
                     &aS[c * 2048 + wave * 512]);
            gl_lds16(BT + (size_t)(n0 + c * 32 + wave * 8 + srow) * Kd + k0 + csw * 8,
                     &bS[c * 2048 + wave * 512]);
        }
        __syncthreads();   // drains vmcnt -> LDS valid

        #pragma unroll
        for (int ks = 0; ks < 2; ks++) {
            bf16x8 af[4], bf[4];
            const int cp = ((ks * 4 + quad) ^ (row & 7)) * 8;   // swizzled read chunk
            #pragma unroll
            for (int t = 0; t < 4; t++) {
                af[t] = *(const bf16x8*)(aS + (wm * 64 + t * 16 + row) * 64 + cp);
                bf[t] = *(const bf16x8*)(bS + (wn * 64 + t * 16 + row) * 64 + cp);
            }
            #pragma unroll
            for (int i = 0; i < 4; i++)
                #pragma unroll
                for (int j = 0; j < 4; j++)
                    acc[i][j] = __builtin_amdgcn_mfma_f32_16x16x32_bf16(af[i], bf[j], acc[i][j], 0, 0, 0);
        }
    }

    if (mode == 0) {
        #pragma unroll
        for (int j = 0; j < 4; j++) {
            const int n  = n0 + wn * 64 + j * 16 + row;
            const float bi = bias[n];
            const int which = n >> 10;
            const int rem   = n & 1023;
            const int h     = rem >> 6;
            const int d     = rem & 63;
            #pragma unroll
            for (int i = 0; i < 4; i++) {
                const int mbase = m0 + wm * 64 + i * 16 + quad * 4;
                #pragma unroll
                for (int r = 0; r < 4; r++) {
                    const int m = mbase + r;
                    const int b = m >> 11;
                    const int t = m & 2047;
                    const int bh = b * NHEADS + h;
                    const float v = acc[i][j][r] + bi;
                    if (which == 0) {
                        Oq[((size_t)bh * T_SEQ + t) * HDIM + d] = f2b(v * QSCALE);
                    } else if (which == 1) {
                        Ok[((size_t)bh * T_SEQ + t) * HDIM + d] = f2b(v);
                    } else {
                        Ov[((size_t)bh * HDIM + d) * T_SEQ + t] = f2b(v);
                    }
                }
            }
        }
    } else {
        #pragma unroll
        for (int j = 0; j < 4; j++) {
            const int n  = n0 + wn * 64 + j * 16 + row;
            const float bi = bias[n];
            #pragma unroll
            for (int i = 0; i < 4; i++) {
                const int mbase = m0 + wm * 64 + i * 16 + quad * 4;
                #pragma unroll
                for (int r = 0; r < 4; r++)
                    Of[(size_t)(mbase + r) * N + n] = acc[i][j][r] + bi;
            }
        }
    }
}

// ---------------------------------------------------------------------------
// MFMA flash attention — R16: 8-wave blocks, 2 tiles/wave, mirrored per-wave.
// Block P in 0..7, wave w in 0..7: H-tile rows [128(15-P)+16w, +16),
// L-tile rows [128P+16w, +16). Covers all 2048 rows across P (H: upper half,
// L: lower half). Keeps R15's halved iteration count (200/head) AND restores
// occupancy: 512 thr x 2 blocks/CU = 16 waves/CU (launch_bounds(512,4) pins
// VGPR <= 128; 2-tile state measured ~120 in R0). Per-wave work: 2 tiles
// while L alive, 1 tile after; total 34 units for EVERY wave/block (balanced;
// only the per-iter overhead term (32-2P iters) varies). Staging: 512 thr x
// 1 uint4 per operand. kf/vf shared by the wave's two tiles.
// Defer-max + tree-max kept; no setprio (m190 lockstep null).
// ---------------------------------------------------------------------------
__global__ __launch_bounds__(512, 4) void attn_mfma(
    const unsigned short* __restrict__ Q,   // [bh][t][64] bf16 (scaled, log2e)
    const unsigned short* __restrict__ K,   // [bh][t][64] bf16
    const unsigned short* __restrict__ VT,  // [bh][64][T] bf16
    unsigned short* __restrict__ Out)       // [B*T][DMODEL] bf16
{
    __shared__ __align__(16) unsigned short kS[2][64 * 72];
    __shared__ __align__(16) unsigned short vS[2][64 * 72];

    const int tid  = threadIdx.x;
    const int lane = tid & 63;
    const int wave = tid >> 6;       // 0..7
    const int row  = lane & 15;
    const int quad = lane >> 4;

    const int bh = blockIdx.x;
    const int b  = bh >> 4;
    const int h  = bh & 15;
    const int P  = blockIdx.y;                 // 0..7
    const int q0H = 128 * (15 - P) + 16 * wave;   // upper-half tile
    const int q0L = 128 * P        + 16 * wave;   // lower-half tile
    const int kend = 128 * (15 - P) + 128;        // WG-uniform loop bound

    const size_t qkbase = (size_t)bh * T_SEQ * HDIM;
    const size_t vtbase = (size_t)bh * HDIM * T_SEQ;

    // staging geometry: 512 threads cover one 64x64 tile per operand
    const int krow0 = tid >> 3;          // 0..63
    const int c0    = tid & 7;           // 0..7
    const int lds0  = krow0 * 72 + c0 * 8;
    const int flat0 = tid * 8;           // = krow0*64 + c0*8

    // Q fragments
    const unsigned short* qpH = Q + qkbase + (size_t)(q0H + row) * HDIM + quad * 8;
    const bf16x8 qH0 = *(const bf16x8*)qpH;
    const bf16x8 qH1 = *(const bf16x8*)(qpH + 32);
    const unsigned short* qpL = Q + qkbase + (size_t)(q0L + row) * HDIM + quad * 8;
    const bf16x8 qL0 = *(const bf16x8*)qpL;
    const bf16x8 qL1 = *(const bf16x8*)(qpL + 32);

    const f32x4 z = {0.f, 0.f, 0.f, 0.f};
    f32x4 oH[4] = {z, z, z, z};
    f32x4 oL[4] = {z, z, z, z};
    float mH = -1e30f, lH = 0.f, mL = -1e30f, lL = 0.f;

    // prefetch tile 0
    uint4 pk0 = *(const uint4*)(K  + qkbase + flat0);
    uint4 pv0 = *(const uint4*)(VT + vtbase + (size_t)krow0 * T_SEQ + c0 * 8);

    int buf = 0;
    for (int kb = 0; kb < kend; kb += 64) {
        // write staged tile to LDS[buf]
        *(uint4*)&kS[buf][lds0] = pk0;
        *(uint4*)&vS[buf][lds0] = pv0;
        __syncthreads();

        // prefetch next tile (overlaps with compute below)
        if (kb + 64 < kend) {
            const int kn = kb + 64;
            pk0 = *(const uint4*)(K  + qkbase + (size_t)kn * HDIM + flat0);
            pv0 = *(const uint4*)(VT + vtbase + (size_t)krow0 * T_SEQ + kn + c0 * 8);
        }

        const bool actH = (kb <= q0H);       // wave-uniform
        const bool actL = (kb <= q0L);       // wave-uniform

        bf16x4 pfH[4], pfL[4];               // written iff actH / actL

        if (actH) {
            // ---- QK^T from LDS K tile (kf shared by H and L) ----
            f32x4 sH[4], sL[4];
            #pragma unroll
            for (int s = 0; s < 4; s++) {
                const int kbs = kb + s * 16;
                if (kbs <= q0H) {
                    const unsigned short* kp = &kS[buf][(s * 16 + row) * 72 + quad * 8];
                    const bf16x8 kf0 = *(const bf16x8*)kp;
                    const bf16x8 kf1 = *(const bf16x8*)(kp + 32);
                    f32x4 t = z;
                    t = __builtin_amdgcn_mfma_f32_16x16x32_bf16(kf0, qH0, t, 0, 0, 0);
                    t = __builtin_amdgcn_mfma_f32_16x16x32_bf16(kf1, qH1, t, 0, 0, 0);
                    if (kbs == q0H) {
                        #pragma unroll
                        for (int r = 0; r < 4; r++)
                            if (quad * 4 + r > row) t[r] = -1e30f;
                    }
                    sH[s] = t;
                    if (kbs <= q0L) {
                        f32x4 u = z;
                        u = __builtin_amdgcn_mfma_f32_16x16x32_bf16(kf0, qL0, u, 0, 0, 0);
                        u = __builtin_amdgcn_mfma_f32_16x16x32_bf16(kf1, qL1, u, 0, 0, 0);
                        if (kbs == q0L) {
                            #pragma unroll
                            for (int r = 0; r < 4; r++)
                                if (quad * 4 + r > row) u[r] = -1e30f;
                        }
                        sL[s] = u;
                    } else {
                        #pragma unroll
                        for (int r = 0; r < 4; r++) sL[s][r] = -1e30f;
                    }
                } else {
                    #pragma unroll
                    for (int r = 0; r < 4; r++) { sH[s][r] = -1e30f; sL[s][r] = -1e30f; }
                }
            }
            online_softmax(sH, mH, lH, oH, pfH);
            if (actL)
                online_softmax(sL, mL, lL, oL, pfL);

            // ---- PV from LDS V^T tile: vf shared by H and L ----
            #pragma unroll
            for (int s = 0; s < 4; s++) {
                const int kbs = kb + s * 16;
                if (kbs <= q0H) {
                    #pragma unroll
                    for (int dt = 0; dt < 4; dt++) {
                        const bf16x4 vf = *(const bf16x4*)&vS[buf][
                            (dt * 16 + row) * 72 + (s * 2 + (quad >> 1)) * 8 + (quad & 1) * 4];
                        oH[dt] = __builtin_amdgcn_mfma_f32_16x16x16bf16_1k(vf, pfH[s], oH[dt], 0, 0, 0);
                        if (kbs <= q0L)
                            oL[dt] = __builtin_amdgcn_mfma_f32_16x16x16bf16_1k(vf, pfL[s], oL[dt], 0, 0, 0);
                    }
                }
            }
        }

        buf ^= 1;
    }

    // ---- epilogue: both tiles ----
    {
        const float rl = 1.f / lH;
        unsigned short* op = Out + ((size_t)(b * T_SEQ + q0H + row)) * DMODEL + h * HDIM + quad * 4;
        #pragma unroll
        for (int dt = 0; dt < 4; dt++) {
            uint2 u;
            u.x = pack2(oH[dt][0] * rl, oH[dt][1] * rl);
            u.y = pack2(oH[dt][2] * rl, oH[dt][3] * rl);
            *(uint2*)(op + dt * 16) = u;
        }
    }
    {
        const float rl = 1.f / lL;
        unsigned short* op = Out + ((size_t)(b * T_SEQ + q0L + row)) * DMODEL + h * HDIM + quad * 4;
        #pragma unroll
        for (int dt = 0; dt < 4; dt++) {
            uint2 u;
            u.x = pack2(oL[dt][0] * rl, oL[dt][1] * rl);
            u.y = pack2(oL[dt][2] * rl, oL[dt][3] * rl);
            *(uint2*)(op + dt * 16) = u;
        }
    }
}

extern "C" void kernel_launch(void* const* d_in, const int* in_sizes, int n_in,
                              void* d_out, int out_size, void* d_ws, size_t ws_size,
                              hipStream_t stream)
{
    const float* x    = (const float*)d_in[0];
    const float* Wqkv = (const float*)d_in[1];
    const float* bqkv = (const float*)d_in[2];
    const float* Wout = (const float*)d_in[3];
    const float* bout = (const float*)d_in[4];
    float* out = (float*)d_out;

    // workspace (MiB offsets): xb 0..16 | WqkvT 16..22 | WoutT 22..24 |
    // Qb 24..40 | Kb 40..56 | Vt 56..72 | Ab 72..88
    char* ws = (char*)d_ws;
    unsigned short* xb    = (unsigned short*)(ws + (size_t)0  * 1024 * 1024);
    unsigned short* WqkvT = (unsigned short*)(ws + (size_t)16 * 1024 * 1024);
    unsigned short* WoutT = (unsigned short*)(ws + (size_t)22 * 1024 * 1024);
    unsigned short* Qb    = (unsigned short*)(ws + (size_t)24 * 1024 * 1024);
    unsigned short* Kb    = (unsigned short*)(ws + (size_t)40 * 1024 * 1024);
    unsigned short* Vt    = (unsigned short*)(ws + (size_t)56 * 1024 * 1024);
    unsigned short* Ab    = (unsigned short*)(ws + (size_t)72 * 1024 * 1024);

    // 0) converts / transposes
    cvt_bf16<<<dim3(MROWS * DMODEL / 1024), 256, 0, stream>>>(x, xb, MROWS * DMODEL);
    cvt_tr<<<dim3(3 * DMODEL / 32, DMODEL / 32), 256, 0, stream>>>(Wqkv, WqkvT, DMODEL, 3 * DMODEL);
    cvt_tr<<<dim3(DMODEL / 32, DMODEL / 32), 256, 0, stream>>>(Wout, WoutT, DMODEL, DMODEL);

    // 1) qkv = x @ W_qkv + b_qkv -> Qb (scaled, log2e folded), Kb, Vt
    gemm_mfma<<<dim3(3 * DMODEL / 128, MROWS / 128), 256, 0, stream>>>(
        xb, WqkvT, bqkv, 3 * DMODEL, DMODEL, 0, Qb, Kb, Vt, nullptr);

    // 2) causal MFMA flash attention -> Ab bf16 (8 blocks/head, 8 waves each)
    attn_mfma<<<dim3(BATCH * NHEADS, 8), 512, 0, stream>>>(Qb, Kb, Vt, Ab);

    // 3) out = Ab @ W_out + b_out (fp32 out)
    gemm_mfma<<<dim3(DMODEL / 128, MROWS / 128), 256, 0, stream>>>(
        Ab, WoutT, bout, DMODEL, DMODEL, 1, nullptr, nullptr, nullptr, out);
}

// Round 7
// 293.748 us; speedup vs baseline: 1.3791x; 1.0172x over previous
//
#include <hip/hip_runtime.h>
#include <stdint.h>

#define T_SEQ   2048
#define DMODEL  1024
#define NHEADS  16
#define HDIM    64
#define BATCH   4
#define MROWS   (BATCH * T_SEQ)   // 8192
// Q pre-scale: 1/sqrt(64) * log2(e)  (softmax runs in exp2 domain)
#define QSCALE  0.18033688011112042f
// defer-max threshold (log2 units): skip O/l rescale unless max grew by >6
#define DEFER_THR 6.0f

typedef __attribute__((ext_vector_type(4))) short bf16x4;
typedef __attribute__((ext_vector_type(8))) short bf16x8;
typedef __attribute__((ext_vector_type(4))) float f32x4;

__device__ __forceinline__ unsigned short f2b(float f) {
    union { float f; unsigned int i; } x;
    x.f = f;
    unsigned int r = x.i + 0x7FFFu + ((x.i >> 16) & 1u);  // RNE
    return (unsigned short)(r >> 16);
}

// raw v_exp_f32 (input in log2 domain)
__device__ __forceinline__ float fexp2(float x) {
#if __has_builtin(__builtin_amdgcn_exp2f)
    return __builtin_amdgcn_exp2f(x);
#else
    return __expf(x * 0.6931471805599453f);
#endif
}

// pack two fp32 -> packed bf16 pair (low = a, high = b)
__device__ __forceinline__ unsigned int pack2(float a, float b) {
#if __has_builtin(__builtin_amdgcn_cvt_pk_bf16_f32)
    auto r = __builtin_amdgcn_cvt_pk_bf16_f32(a, b);
    unsigned int u;
    __builtin_memcpy(&u, &r, 4);
    return u;
#else
    return ((unsigned int)f2b(a)) | (((unsigned int)f2b(b)) << 16);
#endif
}

// tree max of a 4x f32x4 tile (depth 4; clang fuses pairs to v_max3 where it can)
__device__ __forceinline__ float max16(const f32x4 s[4]) {
    const float a = fmaxf(fmaxf(s[0][0], s[0][1]), fmaxf(s[0][2], s[0][3]));
    const float b = fmaxf(fmaxf(s[1][0], s[1][1]), fmaxf(s[1][2], s[1][3]));
    const float c = fmaxf(fmaxf(s[2][0], s[2][1]), fmaxf(s[2][2], s[2][3]));
    const float d = fmaxf(fmaxf(s[3][0], s[3][1]), fmaxf(s[3][2], s[3][3]));
    return fmaxf(fmaxf(a, b), fmaxf(c, d));
}

// online softmax (exp2 domain) for one 16x(4x16) score tile
__device__ __forceinline__ void online_softmax(
    const f32x4 sg[4], float& m_, float& l_, f32x4 o_[4], bf16x4 pf_[4])
{
    float mc = max16(sg);
    mc = fmaxf(mc, __shfl_xor(mc, 16));
    mc = fmaxf(mc, __shfl_xor(mc, 32));
    if (__any(mc > m_ + DEFER_THR)) {          // defer-max: rescale rarely
        const float mn    = fmaxf(m_, mc);
        const float alpha = fexp2(m_ - mn);
        l_ *= alpha;
        #pragma unroll
        for (int dt = 0; dt < 4; dt++)
            #pragma unroll
            for (int r = 0; r < 4; r++) o_[dt][r] *= alpha;
        m_ = mn;
    }
    float ps = 0.f;
    #pragma unroll
    for (int s = 0; s < 4; s++) {
        const float p0 = fexp2(sg[s][0] - m_);
        const float p1 = fexp2(sg[s][1] - m_);
        const float p2 = fexp2(sg[s][2] - m_);
        const float p3 = fexp2(sg[s][3] - m_);
        ps += (p0 + p1) + (p2 + p3);
        uint2 u;
        u.x = pack2(p0, p1);
        u.y = pack2(p2, p3);
        pf_[s] = *(bf16x4*)&u;
    }
    ps += __shfl_xor(ps, 16);
    ps += __shfl_xor(ps, 32);
    l_ += ps;
}

// async global->LDS, 16 B per lane; dest = lds base (wave-uniform) + lane*16
__device__ __forceinline__ void gl_lds16(const unsigned short* g, unsigned short* l) {
    __builtin_amdgcn_global_load_lds(
        (const __attribute__((address_space(1))) void*)g,
        (__attribute__((address_space(3))) void*)l,
        16, 0, 0);
}

// ---------------------------------------------------------------------------
// fp32 -> bf16 elementwise convert
// ---------------------------------------------------------------------------
__global__ __launch_bounds__(256) void cvt_bf16(
    const float* __restrict__ in, unsigned short* __restrict__ out, int n)
{
    const int i = (blockIdx.x * 256 + threadIdx.x) * 4;
    if (i + 3 < n) {
        const float4 v = *(const float4*)(in + i);
        ushort4 o;
        o.x = f2b(v.x); o.y = f2b(v.y); o.z = f2b(v.z); o.w = f2b(v.w);
        *(ushort4*)(out + i) = o;
    }
}

// ---------------------------------------------------------------------------
// fp32 [K][N] -> bf16 [N][K] transpose+convert, 32x32 LDS tile
// ---------------------------------------------------------------------------
__global__ __launch_bounds__(256) void cvt_tr(
    const float* __restrict__ W, unsigned short* __restrict__ WT, int K, int N)
{
    __shared__ unsigned short s[32][33];
    const int n0 = blockIdx.x * 32, k0 = blockIdx.y * 32;
    const int tx = threadIdx.x & 31, ty = threadIdx.x >> 5;   // ty 0..7
    #pragma unroll
    for (int i = 0; i < 4; i++)
        s[ty + 8 * i][tx] = f2b(W[(size_t)(k0 + ty + 8 * i) * N + n0 + tx]);
    __syncthreads();
    #pragma unroll
    for (int i = 0; i < 4; i++)
        WT[(size_t)(n0 + ty + 8 * i) * K + k0 + tx] = s[tx][ty + 8 * i];
}

// ---------------------------------------------------------------------------
// bf16 MFMA GEMM: C[M][NCOLS] = A[M][KD] * BT[NCOLS][KD]^T + bias[NCOLS]
// 128x128 tile, BK=64 (verified R14). 256 thr = 4 waves (2x2).
// R17: KD/NCOLS/MODE are COMPILE-TIME -> address math strength-reduces to
// shifts; global staging pointers hoisted out of the k-loop and advanced by
// +64/iter (kills the ~128 VALU instrs/step of rebuilt 64-bit addresses
// that capped MfmaUtil at 20%, VALUBusy 32% in R6 counters).
// 16 gl_lds16 calls per buffer; XOR swizzle c^(row&7) on source + read side.
// ---------------------------------------------------------------------------
template<int KD, int NCOLS, int MODE>
__global__ __launch_bounds__(256) void gemm_mfma(
    const unsigned short* __restrict__ A,
    const unsigned short* __restrict__ BT,
    const float* __restrict__ bias,
    unsigned short* __restrict__ Oq,
    unsigned short* __restrict__ Ok,
    unsigned short* __restrict__ Ov,
    float* __restrict__ Of)
{
    __shared__ __align__(16) unsigned short aS[128 * 64];
    __shared__ __align__(16) unsigned short bS[128 * 64];

    const int tid  = threadIdx.x;
    const int lane = tid & 63;
    const int wave = tid >> 6;
    const int row  = lane & 15;
    const int quad = lane >> 4;
    const int wm   = wave >> 1;
    const int wn   = wave & 1;
    const int m0   = blockIdx.y * 128;
    const int n0   = blockIdx.x * 128;

    // staging geometry: one gload = 64 lanes x 16B = 8 rows x 64 k (128B/row)
    const int srow = lane >> 3;            // 0..7  local row
    const int c8   = lane & 7;             // 0..7  dest chunk (16B units)
    const int csw  = c8 ^ srow;            // pre-swizzled SOURCE chunk

    // hoisted global staging pointers (advance by 64 elements per K-step)
    const unsigned short* aG = A  + (size_t)(m0 + wave * 8 + srow) * KD + csw * 8;
    const unsigned short* bG = BT + (size_t)(n0 + wave * 8 + srow) * KD + csw * 8;

    f32x4 acc[4][4];
    const f32x4 z = {0.f, 0.f, 0.f, 0.f};
    #pragma unroll
    for (int i = 0; i < 4; i++)
        #pragma unroll
        for (int j = 0; j < 4; j++) acc[i][j] = z;

    for (int k0 = 0; k0 < KD; k0 += 64) {
        __syncthreads();   // all waves done reading previous tile
        #pragma unroll
        for (int c = 0; c < 4; c++) {
            gl_lds16(aG + c * (32 * KD), &aS[c * 2048 + wave * 512]);
            gl_lds16(bG + c * (32 * KD), &bS[c * 2048 + wave * 512]);
        }
        __syncthreads();   // drains vmcnt -> LDS valid
        aG += 64;
        bG += 64;

        #pragma unroll
        for (int ks = 0; ks < 2; ks++) {
            bf16x8 af[4], bf[4];
            const int cp = ((ks * 4 + quad) ^ (row & 7)) * 8;   // swizzled read chunk
            #pragma unroll
            for (int t = 0; t < 4; t++) {
                af[t] = *(const bf16x8*)(aS + (wm * 64 + t * 16 + row) * 64 + cp);
                bf[t] = *(const bf16x8*)(bS + (wn * 64 + t * 16 + row) * 64 + cp);
            }
            #pragma unroll
            for (int i = 0; i < 4; i++)
                #pragma unroll
                for (int j = 0; j < 4; j++)
                    acc[i][j] = __builtin_amdgcn_mfma_f32_16x16x32_bf16(af[i], bf[j], acc[i][j], 0, 0, 0);
        }
    }

    if (MODE == 0) {
        #pragma unroll
        for (int j = 0; j < 4; j++) {
            const int n  = n0 + wn * 64 + j * 16 + row;
            const float bi = bias[n];
            const int which = n >> 10;
            const int rem   = n & 1023;
            const int h     = rem >> 6;
            const int d     = rem & 63;
            #pragma unroll
            for (int i = 0; i < 4; i++) {
                const int mbase = m0 + wm * 64 + i * 16 + quad * 4;
                #pragma unroll
                for (int r = 0; r < 4; r++) {
                    const int m = mbase + r;
                    const int b = m >> 11;
                    const int t = m & 2047;
                    const int bh = b * NHEADS + h;
                    const float v = acc[i][j][r] + bi;
                    if (which == 0) {
                        Oq[((size_t)bh * T_SEQ + t) * HDIM + d] = f2b(v * QSCALE);
                    } else if (which == 1) {
                        Ok[((size_t)bh * T_SEQ + t) * HDIM + d] = f2b(v);
                    } else {
                        Ov[((size_t)bh * HDIM + d) * T_SEQ + t] = f2b(v);
                    }
                }
            }
        }
    } else {
        #pragma unroll
        for (int j = 0; j < 4; j++) {
            const int n  = n0 + wn * 64 + j * 16 + row;
            const float bi = bias[n];
            #pragma unroll
            for (int i = 0; i < 4; i++) {
                const int mbase = m0 + wm * 64 + i * 16 + quad * 4;
                #pragma unroll
                for (int r = 0; r < 4; r++)
                    Of[(size_t)(mbase + r) * NCOLS + n] = acc[i][j][r] + bi;
            }
        }
    }
}

// ---------------------------------------------------------------------------
// MFMA flash attention — R16 (verified 298.8 total): 8-wave blocks, 2
// tiles/wave, mirrored per-wave. Block P in 0..7, wave w: H-tile rows
// [128(15-P)+16w,+16), L-tile rows [128P+16w,+16). 200 iters/head; 512 thr,
// launch_bounds(512,4) -> 16 waves/CU. kf/vf shared by the wave's two tiles.
// Defer-max + tree-max kept; no setprio (m190 lockstep null).
// ---------------------------------------------------------------------------
__global__ __launch_bounds__(512, 4) void attn_mfma(
    const unsigned short* __restrict__ Q,   // [bh][t][64] bf16 (scaled, log2e)
    const unsigned short* __restrict__ K,   // [bh][t][64] bf16
    const unsigned short* __restrict__ VT,  // [bh][64][T] bf16
    unsigned short* __restrict__ Out)       // [B*T][DMODEL] bf16
{
    __shared__ __align__(16) unsigned short kS[2][64 * 72];
    __shared__ __align__(16) unsigned short vS[2][64 * 72];

    const int tid  = threadIdx.x;
    const int lane = tid & 63;
    const int wave = tid >> 6;       // 0..7
    const int row  = lane & 15;
    const int quad = lane >> 4;

    const int bh = blockIdx.x;
    const int b  = bh >> 4;
    const int h  = bh & 15;
    const int P  = blockIdx.y;                 // 0..7
    const int q0H = 128 * (15 - P) + 16 * wave;   // upper-half tile
    const int q0L = 128 * P        + 16 * wave;   // lower-half tile
    const int kend = 128 * (15 - P) + 128;        // WG-uniform loop bound

    const size_t qkbase = (size_t)bh * T_SEQ * HDIM;
    const size_t vtbase = (size_t)bh * HDIM * T_SEQ;

    // staging geometry: 512 threads cover one 64x64 tile per operand
    const int krow0 = tid >> 3;          // 0..63
    const int c0    = tid & 7;           // 0..7
    const int lds0  = krow0 * 72 + c0 * 8;
    const int flat0 = tid * 8;           // = krow0*64 + c0*8

    // Q fragments
    const unsigned short* qpH = Q + qkbase + (size_t)(q0H + row) * HDIM + quad * 8;
    const bf16x8 qH0 = *(const bf16x8*)qpH;
    const bf16x8 qH1 = *(const bf16x8*)(qpH + 32);
    const unsigned short* qpL = Q + qkbase + (size_t)(q0L + row) * HDIM + quad * 8;
    const bf16x8 qL0 = *(const bf16x8*)qpL;
    const bf16x8 qL1 = *(const bf16x8*)(qpL + 32);

    const f32x4 z = {0.f, 0.f, 0.f, 0.f};
    f32x4 oH[4] = {z, z, z, z};
    f32x4 oL[4] = {z, z, z, z};
    float mH = -1e30f, lH = 0.f, mL = -1e30f, lL = 0.f;

    // prefetch tile 0
    uint4 pk0 = *(const uint4*)(K  + qkbase + flat0);
    uint4 pv0 = *(const uint4*)(VT + vtbase + (size_t)krow0 * T_SEQ + c0 * 8);

    int buf = 0;
    for (int kb = 0; kb < kend; kb += 64) {
        // write staged tile to LDS[buf]
        *(uint4*)&kS[buf][lds0] = pk0;
        *(uint4*)&vS[buf][lds0] = pv0;
        __syncthreads();

        // prefetch next tile (overlaps with compute below)
        if (kb + 64 < kend) {
            const int kn = kb + 64;
            pk0 = *(const uint4*)(K  + qkbase + (size_t)kn * HDIM + flat0);
            pv0 = *(const uint4*)(VT + vtbase + (size_t)krow0 * T_SEQ + kn + c0 * 8);
        }

        const bool actH = (kb <= q0H);       // wave-uniform
        const bool actL = (kb <= q0L);       // wave-uniform

        bf16x4 pfH[4], pfL[4];               // written iff actH / actL

        if (actH) {
            // ---- QK^T from LDS K tile (kf shared by H and L) ----
            f32x4 sH[4], sL[4];
            #pragma unroll
            for (int s = 0; s < 4; s++) {
                const int kbs = kb + s * 16;
                if (kbs <= q0H) {
                    const unsigned short* kp = &kS[buf][(s * 16 + row) * 72 + quad * 8];
                    const bf16x8 kf0 = *(const bf16x8*)kp;
                    const bf16x8 kf1 = *(const bf16x8*)(kp + 32);
                    f32x4 t = z;
                    t = __builtin_amdgcn_mfma_f32_16x16x32_bf16(kf0, qH0, t, 0, 0, 0);
                    t = __builtin_amdgcn_mfma_f32_16x16x32_bf16(kf1, qH1, t, 0, 0, 0);
                    if (kbs == q0H) {
                        #pragma unroll
                        for (int r = 0; r < 4; r++)
                            if (quad * 4 + r > row) t[r] = -1e30f;
                    }
                    sH[s] = t;
                    if (kbs <= q0L) {
                        f32x4 u = z;
                        u = __builtin_amdgcn_mfma_f32_16x16x32_bf16(kf0, qL0, u, 0, 0, 0);
                        u = __builtin_amdgcn_mfma_f32_16x16x32_bf16(kf1, qL1, u, 0, 0, 0);
                        if (kbs == q0L) {
                            #pragma unroll
                            for (int r = 0; r < 4; r++)
                                if (quad * 4 + r > row) u[r] = -1e30f;
                        }
                        sL[s] = u;
                    } else {
                        #pragma unroll
                        for (int r = 0; r < 4; r++) sL[s][r] = -1e30f;
                    }
                } else {
                    #pragma unroll
                    for (int r = 0; r < 4; r++) { sH[s][r] = -1e30f; sL[s][r] = -1e30f; }
                }
            }
            online_softmax(sH, mH, lH, oH, pfH);
            if (actL)
                online_softmax(sL, mL, lL, oL, pfL);

            // ---- PV from LDS V^T tile: vf shared by H and L ----
            #pragma unroll
            for (int s = 0; s < 4; s++) {
                const int kbs = kb + s * 16;
                if (kbs <= q0H) {
                    #pragma unroll
                    for (int dt = 0; dt < 4; dt++) {
                        const bf16x4 vf = *(const bf16x4*)&vS[buf][
                            (dt * 16 + row) * 72 + (s * 2 + (quad >> 1)) * 8 + (quad & 1) * 4];
                        oH[dt] = __builtin_amdgcn_mfma_f32_16x16x16bf16_1k(vf, pfH[s], oH[dt], 0, 0, 0);
                        if (kbs <= q0L)
                            oL[dt] = __builtin_amdgcn_mfma_f32_16x16x16bf16_1k(vf, pfL[s], oL[dt], 0, 0, 0);
                    }
                }
            }
        }

        buf ^= 1;
    }

    // ---- epilogue: both tiles ----
    {
        const float rl = 1.f / lH;
        unsigned short* op = Out + ((size_t)(b * T_SEQ + q0H + row)) * DMODEL + h * HDIM + quad * 4;
        #pragma unroll
        for (int dt = 0; dt < 4; dt++) {
            uint2 u;
            u.x = pack2(oH[dt][0] * rl, oH[dt][1] * rl);
            u.y = pack2(oH[dt][2] * rl, oH[dt][3] * rl);
            *(uint2*)(op + dt * 16) = u;
        }
    }
    {
        const float rl = 1.f / lL;
        unsigned short* op = Out + ((size_t)(b * T_SEQ + q0L + row)) * DMODEL + h * HDIM + quad * 4;
        #pragma unroll
        for (int dt = 0; dt < 4; dt++) {
            uint2 u;
            u.x = pack2(oL[dt][0] * rl, oL[dt][1] * rl);
            u.y = pack2(oL[dt][2] * rl, oL[dt][3] * rl);
            *(uint2*)(op + dt * 16) = u;
        }
    }
}

extern "C" void kernel_launch(void* const* d_in, const int* in_sizes, int n_in,
                              void* d_out, int out_size, void* d_ws, size_t ws_size,
                              hipStream_t stream)
{
    const float* x    = (const float*)d_in[0];
    const float* Wqkv = (const float*)d_in[1];
    const float* bqkv = (const float*)d_in[2];
    const float* Wout = (const float*)d_in[3];
    const float* bout = (const float*)d_in[4];
    float* out = (float*)d_out;

    // workspace (MiB offsets): xb 0..16 | WqkvT 16..22 | WoutT 22..24 |
    // Qb 24..40 | Kb 40..56 | Vt 56..72 | Ab 72..88
    char* ws = (char*)d_ws;
    unsigned short* xb    = (unsigned short*)(ws + (size_t)0  * 1024 * 1024);
    unsigned short* WqkvT = (unsigned short*)(ws + (size_t)16 * 1024 * 1024);
    unsigned short* WoutT = (unsigned short*)(ws + (size_t)22 * 1024 * 1024);
    unsigned short* Qb    = (unsigned short*)(ws + (size_t)24 * 1024 * 1024);
    unsigned short* Kb    = (unsigned short*)(ws + (size_t)40 * 1024 * 1024);
    unsigned short* Vt    = (unsigned short*)(ws + (size_t)56 * 1024 * 1024);
    unsigned short* Ab    = (unsigned short*)(ws + (size_t)72 * 1024 * 1024);

    // 0) converts / transposes
    cvt_bf16<<<dim3(MROWS * DMODEL / 1024), 256, 0, stream>>>(x, xb, MROWS * DMODEL);
    cvt_tr<<<dim3(3 * DMODEL / 32, DMODEL / 32), 256, 0, stream>>>(Wqkv, WqkvT, DMODEL, 3 * DMODEL);
    cvt_tr<<<dim3(DMODEL / 32, DMODEL / 32), 256, 0, stream>>>(Wout, WoutT, DMODEL, DMODEL);

    // 1) qkv = x @ W_qkv + b_qkv -> Qb (scaled, log2e folded), Kb, Vt
    gemm_mfma<DMODEL, 3 * DMODEL, 0><<<dim3(3 * DMODEL / 128, MROWS / 128), 256, 0, stream>>>(
        xb, WqkvT, bqkv, Qb, Kb, Vt, nullptr);

    // 2) causal MFMA flash attention -> Ab bf16 (8 blocks/head, 8 waves each)
    attn_mfma<<<dim3(BATCH * NHEADS, 8), 512, 0, stream>>>(Qb, Kb, Vt, Ab);

    // 3) out = Ab @ W_out + b_out (fp32 out)
    gemm_mfma<DMODEL, DMODEL, 1><<<dim3(DMODEL / 128, MROWS / 128), 256, 0, stream>>>(
        Ab, WoutT, bout, nullptr, nullptr, nullptr, out);
}